// Round 3
// baseline (453.527 us; speedup 1.0000x reference)
//
#include <hip/hip_runtime.h>
#include <cstdint>
#include <cstddef>

#define BATCH  8192
#define IN_N   256
#define OUT_N  256
#define LAT_N  128
#define SLABS  129                 // 128 latent slabs + 1 bw slab
#define KT     (SLABS * IN_N)      // 33024 = total K in elements
#define KT16   (KT / 16)           // 2064 k-tiles of 16
#define SPLITK 4

typedef _Float16 h8 __attribute__((ext_vector_type(8)));
typedef _Float16 h4 __attribute__((ext_vector_type(4)));
typedef float    f16v __attribute__((ext_vector_type(16)));
typedef float    f4v  __attribute__((ext_vector_type(4)));

// ws layout (bytes) — identical total footprint to the proven baseline (56,770,560 B)
#define WS_BP    0                 // packed B: 8 nt * 2064 kt * 64 lane * 8 halves * 2B = 16908288
#define WS_XH    16908288          // + 8192*256*2 = 4194304
#define WS_LT    21102592          // + 129*8192*2 = 2113536
#define WS_PARTS 23216128          // + 4 * 8192*256*4 = 33554432  -> total 56770560

// ---------------- K1 (fused prep): three independent jobs, one launch.
//  blocks [0, 2064)          : W transpose+pack into MFMA-fragment order
//  blocks [2064, 2064+6176)  : x->f16, latent->LT (transposed, +ones row)
//  blocks [8240, 8240+1024)  : bias part0[b][o] = latent[b]·Wb[:,o] + bb[o]
//
// Bp[nt][kt16][lane][h]  (lane = kh*32 + n32, h = 0..7)
//   = W2T[o = nt*32 + n32][k = kt16*16 + kh*8 + h]
// where W2T[o][k] = k<32768 ? Ww[k*256+o] : bw[(k-32768)*256+o]
#define PREP_T0   0
#define PREP_T1   2064            // 516 * 4 transpose blocks
#define PREP_C1   8240            // + 6176 convert blocks
#define PREP_B1   9264            // + 1024 bias blocks
__global__ void k_prep(const float* __restrict__ Ww, const float* __restrict__ bw,
                       const float* __restrict__ x,  const float* __restrict__ latent,
                       const float* __restrict__ Wb, const float* __restrict__ bb,
                       _Float16* __restrict__ Bp, _Float16* __restrict__ Xh,
                       _Float16* __restrict__ LT, float* __restrict__ part0) {
    __shared__ float smem[64 * 65];         // transpose tile; bias branch reuses first 4KB
    const int bid = blockIdx.x;
    const int t   = threadIdx.x;

    if (bid < PREP_T1) {
        // ---- W transpose + f16 pack
        const int kx = bid % 516, oy = bid / 516;
        const int k0 = kx * 64;             // k tile (516*64 = 33024)
        const int o0 = oy * 64;             // o tile
        const int c  = t & 63, r0 = t >> 6;
        float (*tile)[65] = (float(*)[65])smem;
#pragma unroll
        for (int j = 0; j < 16; ++j) {
            int r = r0 + 4 * j;
            int k = k0 + r;
            float v;
            if (k < LAT_N * IN_N) v = Ww[(size_t)k * 256 + o0 + c];
            else                  v = bw[(size_t)(k - LAT_N * IN_N) * 256 + o0 + c];
            tile[r][c] = v;                 // tile[k - k0][o - o0]
        }
        __syncthreads();
        const int tl = t & 31, st = t >> 5;
        const int kt_l = st >> 1, nt_l = st & 1;
        const int nt   = oy * 2 + nt_l;     // 0..7
        const int kt16 = kx * 4 + kt_l;     // 0..2063
        _Float16* dst = Bp + ((size_t)(nt * KT16 + kt16) * 64) * 8;
#pragma unroll
        for (int kh = 0; kh < 2; ++kh) {
            h8 v;
#pragma unroll
            for (int h = 0; h < 8; ++h)
                v[h] = (_Float16)tile[kt_l * 16 + kh * 8 + h][nt_l * 32 + tl];
            *(h8*)(dst + (size_t)(kh * 32 + tl) * 8) = v;
        }
    } else if (bid < PREP_C1) {
        // ---- conversions
        const int cb = bid - PREP_T1;
        if (cb < 2048) {                    // x: 2M elems, 4 per thread
            int i = (cb * 256 + t) * 4;
            float4 v = *(const float4*)(x + i);
            h4 o;
            o[0] = (_Float16)v.x; o[1] = (_Float16)v.y;
            o[2] = (_Float16)v.z; o[3] = (_Float16)v.w;
            *(h4*)(Xh + i) = o;
        } else if (cb < 2048 + 4096) {      // latent transpose: 1M elems
            int i = (cb - 2048) * 256 + t;
            int b = i >> 7, l = i & 127;
            LT[(size_t)l * BATCH + b] = (_Float16)latent[i];
        } else {                            // ones row: 8192 elems
            int b = (cb - 2048 - 4096) * 256 + t;
            LT[(size_t)LAT_N * BATCH + b] = (_Float16)1.0f;
        }
    } else {
        // ---- bias into split-0 partial
        float (*lat)[128] = (float(*)[128])smem;
        const int b0 = (bid - PREP_C1) * 8; // 1024 blocks
#pragma unroll
        for (int j = 0; j < 4; ++j) {
            int idx = t + 256 * j;          // 0..1023
            int rr = idx >> 7, l = idx & 127;
            lat[rr][l] = latent[(size_t)(b0 + rr) * 128 + l];
        }
        __syncthreads();
        const int o = t;
        float acc[8];
        float bbv = bb[o];
#pragma unroll
        for (int rr = 0; rr < 8; ++rr) acc[rr] = bbv;
        for (int l = 0; l < 128; ++l) {
            float w = Wb[l * 256 + o];
#pragma unroll
            for (int rr = 0; rr < 8; ++rr) acc[rr] += lat[rr][l] * w;
        }
#pragma unroll
        for (int rr = 0; rr < 8; ++rr) part0[(size_t)(b0 + rr) * 256 + o] = acc[rr];
    }
}

// ---------------- K2: main GEMM. Block: 512 threads (8 waves), 64 rows x 256 cols,
// split-K=4 over slabs. Grid 512 = 128 m-blocks x 4 ks -> 2 blocks/CU (LDS 2x32KB,
// VGPR<=128 via bounds) -> 4 waves/SIMD for latency hiding.
// Each wave owns a 64x32 output strip: one coalesced 1KB B-fragment load + 2 MFMAs
// per inner iter (AI = 64 FLOP per L2 byte -> ~20 TB/s L2 demand at 60% MfmaUtil).
// A (x) in LDS (swizzled, loaded once, barrier-free K loop). ks = bid&3 keeps each
// XCD's resident blocks on a single 4.2MB B-slice (~its private L2).
__global__ __launch_bounds__(512, 4) void k_gemm(const _Float16* __restrict__ Bp,
                                                 const _Float16* __restrict__ Xh,
                                                 const _Float16* __restrict__ LT,
                                                 float* __restrict__ parts) {
    __shared__ _Float16 Xs[64 * 256];       // 32 KB

    const int bid   = blockIdx.x;           // 512 blocks
    const int m_blk = bid >> 2;             // 0..127
    const int ks    = bid & 3;
    const int m0    = m_blk * 64;
    const int slab0 = (ks == 0) ? 0 : 33 + 32 * (ks - 1);
    const int nslab = (ks == 0) ? 33 : 32;  // 33 + 3*32 = 129

    const int tid = threadIdx.x, wid = tid >> 6, lane = tid & 63;
    const int l32 = lane & 31, khalf = lane >> 5;

    // ---- stage X tile into LDS with 16B-granule XOR swizzle (granule g stored at slot g^(m&7))
    for (int j = 0; j < 4; ++j) {
        int G = j * 512 + tid;              // 2048 granules total
        int m = G >> 5, gp = G & 31;
        int g = gp ^ (m & 7);
        h8 v = *(const h8*)(Xh + (size_t)(m0 + m) * IN_N + g * 8);
        *(h8*)(Xs + m * IN_N + gp * 8) = v;
    }
    __syncthreads();

    // per-lane rows (A side): m = t*32 + l32, t in {0,1}
    int mrow[2], m7[2], pbase[2], m6[2];
#pragma unroll
    for (int t = 0; t < 2; ++t) {
        mrow[t]  = t * 32 + l32;
        m7[t]    = mrow[t] & 7;
        m6[t]    = m7[t] & 6;
        pbase[t] = mrow[t] * IN_N + (khalf ^ (m7[t] & 1)) * 8;
    }

    // latent scalars for this block's rows
    const _Float16* ltp = LT + (size_t)slab0 * BATCH + m0;
    _Float16 s_cur[2], s_nxt[2];
#pragma unroll
    for (int t = 0; t < 2; ++t) s_cur[t] = ltp[mrow[t]];

    // B pointer (packed layout): fragment for (col-tile nt=wid, k-tile kt) at
    // Bp + ((nt*KT16 + kt)*64 + lane)*8  -- lane-contiguous 16B each.
    const _Float16* bp = Bp + ((size_t)(wid * KT16 + slab0 * 16) * 64 + lane) * 8;

    f16v acc[2];
#pragma unroll
    for (int t = 0; t < 2; ++t)
#pragma unroll
        for (int r = 0; r < 16; ++r) acc[t][r] = 0.0f;

    for (int sl = 0; sl < nslab; ++sl) {
        if (sl) {
#pragma unroll
            for (int t = 0; t < 2; ++t) s_cur[t] = s_nxt[t];
        }
        if (sl + 1 < nslab) {
            const _Float16* p = ltp + (size_t)(sl + 1) * BATCH;
#pragma unroll
            for (int t = 0; t < 2; ++t) s_nxt[t] = p[mrow[t]];
        }
        h8 s8[2];
#pragma unroll
        for (int t = 0; t < 2; ++t) {
            _Float16 s = s_cur[t];
            s8[t][0]=s; s8[t][1]=s; s8[t][2]=s; s8[t][3]=s;
            s8[t][4]=s; s8[t][5]=s; s8[t][6]=s; s8[t][7]=s;
        }
        const _Float16* bsl = bp + (size_t)sl * (16 * 512);
#pragma unroll
        for (int ks16 = 0; ks16 < 16; ++ks16) {
            h8 b = *(const h8*)(bsl + ks16 * 512);
            h8 a[2];
#pragma unroll
            for (int t = 0; t < 2; ++t) {
                int off = pbase[t] + ((ks16 * 2) ^ m6[t]) * 8;
                h8 xv = *(const h8*)(Xs + off);
                a[t] = xv * s8[t];
            }
#pragma unroll
            for (int t = 0; t < 2; ++t)
                acc[t] = __builtin_amdgcn_mfma_f32_32x32x16_f16(a[t], b, acc[t], 0, 0, 0);
        }
    }

    // epilogue: write partials; split 0 accumulates onto pre-written bias
    float* dst = parts + (size_t)ks * ((size_t)BATCH * OUT_N);
#pragma unroll
    for (int t = 0; t < 2; ++t) {
        int rowb = m0 + t * 32;
        int col  = wid * 32 + l32;
#pragma unroll
        for (int r = 0; r < 16; ++r) {
            int row = rowb + (r & 3) + 8 * (r >> 2) + 4 * khalf;
            size_t off = (size_t)row * OUT_N + col;
            float v = acc[t][r];
            if (ks == 0) dst[off] += v;
            else         dst[off] = v;
        }
    }
}

// ---------------- K3: out = sum of 4 partials
__global__ void k_reduce(const float* __restrict__ parts, float* __restrict__ out) {
    int i = (blockIdx.x * 256 + threadIdx.x) * 4;
    f4v s = *(const f4v*)(parts + i);
    s += *(const f4v*)(parts + 2097152 + i);
    s += *(const f4v*)(parts + 2 * 2097152 + i);
    s += *(const f4v*)(parts + 3 * 2097152 + i);
    *(f4v*)(out + i) = s;
}

extern "C" void kernel_launch(void* const* d_in, const int* in_sizes, int n_in,
                              void* d_out, int out_size, void* d_ws, size_t ws_size,
                              hipStream_t stream) {
    const float* x      = (const float*)d_in[0];
    const float* latent = (const float*)d_in[1];
    const float* Ww     = (const float*)d_in[2];
    const float* bw     = (const float*)d_in[3];
    const float* Wb     = (const float*)d_in[4];
    const float* bb     = (const float*)d_in[5];

    char* ws = (char*)d_ws;
    _Float16* Bp    = (_Float16*)(ws + WS_BP);
    _Float16* Xh    = (_Float16*)(ws + WS_XH);
    _Float16* LT    = (_Float16*)(ws + WS_LT);
    float*    parts = (float*)(ws + WS_PARTS);
    float*    out   = (float*)d_out;

    k_prep<<<PREP_B1, 256, 0, stream>>>(Ww, bw, x, latent, Wb, bb, Bp, Xh, LT, parts);
    k_gemm<<<512, 512, 0, stream>>>(Bp, Xh, LT, parts);
    k_reduce<<<2048, 256, 0, stream>>>(parts, out);
}